// Round 12
// baseline (520.018 us; speedup 1.0000x reference)
//
#include <hip/hip_runtime.h>
#include <hip/hip_bf16.h>

#define T_DIM 4096
#define B_DIM 32
#define I_DIM 512
#define O_DIM 512
#define M_DIM (T_DIM * B_DIM)   // 131072
#define PARAM 0.1f
#define ISCALE 1.1111112f       // 1/(1-p)

#define STRIP 32
#define TAPS 8                  // p^8 = 1e-8 << bf16 eps

typedef __attribute__((ext_vector_type(8))) short bf16x8;
typedef __attribute__((ext_vector_type(4))) float f32x4;

__device__ __forceinline__ unsigned short f2bf(float f) {
    union { __hip_bfloat16 b; unsigned short u; } cv;
    cv.b = __float2bfloat16(f);
    return cv.u;
}

// --- W fp32 -> bf16 (0.5 MB, ws offset 0) ---
__global__ __launch_bounds__(256) void wcvt_kernel(const float* __restrict__ W,
                                                   unsigned short* __restrict__ Wb) {
    const int i = (blockIdx.x * 256 + threadIdx.x) * 4;
    f32x4 v = *(const f32x4*)(W + i);
    ushort4 o;
    o.x = f2bf(v[0]); o.y = f2bf(v[1]); o.z = f2bf(v[2]); o.w = f2bf(v[3]);
    *(ushort4*)(Wb + i) = o;
}

// --- EMA over raw X (linearity: EMA(XW+b) = EMA(X)W + s[t]*b). Strip-parallel,
// TAPS warm-up reads raw X; bf16 output compacted into d_ws. ---
__global__ __launch_bounds__(256) void xema_kernel(const float* __restrict__ X,
                                                   unsigned short* __restrict__ Xv) {
    const int s   = blockIdx.x >> 4;                 // strip 0..127
    const int blk = blockIdx.x & 15;
    const int col = (blk * 256 + threadIdx.x) * 4;
    const int t0  = s * STRIP;
    const int b   = col >> 9;
    const int o   = col & 511;

    const float* xin = X + (size_t)t0 * 16384 + col;
    unsigned short* xout = Xv + (size_t)(t0 * 32 + b) * 512 + o;

    f32x4 v = {0.f, 0.f, 0.f, 0.f};
    if (s > 0) {
        const float* w = xin - (size_t)TAPS * 16384;
        #pragma unroll
        for (int j = 0; j < TAPS; ++j)
            v = PARAM * v + *(const f32x4*)(w + (size_t)j * 16384);
    }

    f32x4 bufA[4], bufB[4];
    #pragma unroll
    for (int j = 0; j < 4; ++j) bufA[j] = *(const f32x4*)(xin + (size_t)j * 16384);

    #pragma unroll
    for (int i = 0; i < STRIP; i += 8) {
        #pragma unroll
        for (int j = 0; j < 4; ++j)
            bufB[j] = *(const f32x4*)(xin + (size_t)(i + 4 + j) * 16384);
        #pragma unroll
        for (int j = 0; j < 4; ++j) {
            v = PARAM * v + bufA[j];
            ushort4 pk; pk.x = f2bf(v[0]); pk.y = f2bf(v[1]); pk.z = f2bf(v[2]); pk.w = f2bf(v[3]);
            *(ushort4*)(xout + (size_t)(i + j) * 16384) = pk;
        }
        if (i + 8 < STRIP) {
            #pragma unroll
            for (int j = 0; j < 4; ++j)
                bufA[j] = *(const f32x4*)(xin + (size_t)(i + 8 + j) * 16384);
        }
        #pragma unroll
        for (int j = 0; j < 4; ++j) {
            v = PARAM * v + bufB[j];
            ushort4 pk; pk.x = f2bf(v[0]); pk.y = f2bf(v[1]); pk.z = f2bf(v[2]); pk.w = f2bf(v[3]);
            *(ushort4*)(xout + (size_t)(i + 4 + j) * 16384) = pk;
        }
    }
}

// --- GEMM: B-panel-resident, barrier-free main loop. Each block owns 64 W-cols
// x full K (64KB LDS, staged ONCE via global_load_lds + one __syncthreads) and
// 2048 Xv rows (4 M-subtiles of 512). 8 waves x wave-tile 64x64 (acc 4x4).
// Main loop: A frags = contiguous 16B global loads (Xv is bf16 in fragment
// order, L2-hot via XCD row-chunk grouping), B frags from read-only LDS, 32
// MFMA per ks — ZERO barriers, waves free-run, 4 waves/SIMD hide latency.
// XCD map: bid&7 = xcd; all 8 col-groups of a row-chunk on one XCD. ---
__global__ __launch_bounds__(512, 4) void gemm_kernel(const unsigned short* __restrict__ Xv,
                                                      const unsigned short* __restrict__ Wb,
                                                      const float* __restrict__ bias,
                                                      float* __restrict__ Y) {
    __shared__ __align__(16) short Bs[64 * 512];   // 64 KB: 64 W-cols x K=512

    const int tid  = threadIdx.x;
    const int lane = tid & 63;
    const int wave = tid >> 6;                 // 0..7 = M-sub-row group

    const int xcd  = blockIdx.x & 7;
    const int idx  = blockIdx.x >> 3;          // 0..63
    const int colg = idx & 7;                  // col-group within XCD
    const int rowc = idx >> 3;                 // row-chunk within XCD
    const int rowB = (xcd * 8 + rowc) * 2048;  // block's 2048-row span
    const int col0 = colg * 64;

    // --- Stage B panel once: 8 rounds x 512 thr x 16B. Pre-swizzled source
    // (involution on low 3 chunk bits, window = (row&7)) -> linear LDS dest. ---
    {
        const int r8 = tid >> 6;               // row offset within round (0..7)
        const int c  = tid & 63;               // 16B chunk within 1KB row
        const int cs = c ^ (r8 & 7);           // r&7 == (tid>>6)&7 every round
        const unsigned short* gsrc = Wb + (size_t)(col0 + r8) * 512 + cs * 8;
        #pragma unroll
        for (int s_ = 0; s_ < 8; ++s_)
            __builtin_amdgcn_global_load_lds(
                (const __attribute__((address_space(1))) unsigned int*)(gsrc + (size_t)s_ * 8 * 512),
                (__attribute__((address_space(3))) unsigned int*)(Bs + (size_t)s_ * 4096 + tid * 8),
                16, 0, 0);
    }
    __syncthreads();   // the ONLY barrier

    // bias (per-thread 4 cols, reused across all M-subtiles)
    float bv[4];
    #pragma unroll
    for (int nf = 0; nf < 4; ++nf)
        bv[nf] = bias[col0 + nf * 16 + (lane & 15)];

    for (int mt = 0; mt < 4; ++mt) {
        const int row0 = rowB + mt * 512 + wave * 64;
        const unsigned short* aBase =
            Xv + (size_t)(row0 + (lane & 15)) * 512 + ((lane >> 4) << 3);

        f32x4 acc[4][4] = {};

        #pragma unroll
        for (int ks = 0; ks < 8; ++ks) {
            #pragma unroll
            for (int kk = 0; kk < 2; ++kk) {
                bf16x8 a_[4], b_[4];
                #pragma unroll
                for (int mf = 0; mf < 4; ++mf)
                    a_[mf] = *(const bf16x8*)(aBase + (size_t)mf * 16 * 512 + ks * 64 + kk * 32);
                #pragma unroll
                for (int nf = 0; nf < 4; ++nf) {
                    const int r  = nf * 16 + (lane & 15);
                    const int cc = ks * 8 + kk * 4 + (lane >> 4);
                    b_[nf] = *(const bf16x8*)((const char*)Bs + r * 1024 + ((cc ^ (r & 7)) << 4));
                }
                #pragma unroll
                for (int mf = 0; mf < 4; ++mf)
                    #pragma unroll
                    for (int nf = 0; nf < 4; ++nf)
                        acc[mf][nf] = __builtin_amdgcn_mfma_f32_16x16x32_bf16(
                            a_[mf], b_[nf], acc[mf][nf], 0, 0, 0);
            }
        }

        // epilogue: Y = acc + s[t]*bias. t = grow>>5; within 64 rows: tt = mf>>1.
        float sc2[2];
        #pragma unroll
        for (int tt = 0; tt < 2; ++tt) {
            const int t_ = (row0 >> 5) + tt;
            sc2[tt] = (1.0f - __expf(-2.3025851f * (float)(t_ + 1))) * ISCALE;
        }
        #pragma unroll
        for (int mf = 0; mf < 4; ++mf) {
            #pragma unroll
            for (int nf = 0; nf < 4; ++nf) {
                const int gcol = col0 + nf * 16 + (lane & 15);
                #pragma unroll
                for (int j = 0; j < 4; ++j) {
                    const int grow = row0 + mf * 16 + ((lane >> 4) << 2) + j;
                    Y[(size_t)grow * O_DIM + gcol] = acc[mf][nf][j] + sc2[mf >> 1] * bv[nf];
                }
            }
        }
    }
}

extern "C" void kernel_launch(void* const* d_in, const int* in_sizes, int n_in,
                              void* d_out, int out_size, void* d_ws, size_t ws_size,
                              hipStream_t stream) {
    const float* X    = (const float*)d_in[0];
    const float* W    = (const float*)d_in[1];
    const float* bias = (const float*)d_in[2];
    float* Y = (float*)d_out;
    unsigned short* Wb = (unsigned short*)d_ws;                       // 512 KB
    unsigned short* Xv = (unsigned short*)((char*)d_ws + (1 << 20));  // 134 MB

    wcvt_kernel<<<dim3(O_DIM * I_DIM / (256 * 4)), dim3(256), 0, stream>>>(W, Wb);
    xema_kernel<<<dim3((T_DIM / STRIP) * 16), dim3(256), 0, stream>>>(X, Xv);
    gemm_kernel<<<dim3(512), dim3(512), 0, stream>>>(Xv, Wb, bias, Y);
}

// Round 13
// 232.821 us; speedup vs baseline: 2.2336x; 2.2336x over previous
//
#include <hip/hip_runtime.h>
#include <hip/hip_bf16.h>

#define T_DIM 4096
#define B_DIM 32
#define I_DIM 512
#define O_DIM 512
#define M_DIM (T_DIM * B_DIM)   // 131072
#define PARAM 0.1f
#define ISCALE 1.1111112f       // 1/(1-p)

#define STRIP 32
#define TAPS 8                  // p^8 = 1e-8 << bf16 eps

#define BM 128
#define BN 128
#define BK 64
#define NK (I_DIM / BK)         // 8

typedef __attribute__((ext_vector_type(8))) short bf16x8;
typedef __attribute__((ext_vector_type(4))) float f32x4;

__device__ __forceinline__ unsigned short f2bf(float f) {
    union { __hip_bfloat16 b; unsigned short u; } cv;
    cv.b = __float2bfloat16(f);
    return cv.u;
}

// --- W fp32 -> bf16 (0.5 MB, ws offset 0) ---
__global__ __launch_bounds__(256) void wcvt_kernel(const float* __restrict__ W,
                                                   unsigned short* __restrict__ Wb) {
    const int i = (blockIdx.x * 256 + threadIdx.x) * 4;
    f32x4 v = *(const f32x4*)(W + i);
    ushort4 o;
    o.x = f2bf(v[0]); o.y = f2bf(v[1]); o.z = f2bf(v[2]); o.w = f2bf(v[3]);
    *(ushort4*)(Wb + i) = o;
}

// --- EMA over raw X (linearity: EMA(XW+b) = EMA(X)W + s[t]*b). Strip-parallel,
// TAPS warm-up reads raw X; bf16 output compacted into d_ws. ---
__global__ __launch_bounds__(256) void xema_kernel(const float* __restrict__ X,
                                                   unsigned short* __restrict__ Xv) {
    const int s   = blockIdx.x >> 4;                 // strip 0..127
    const int blk = blockIdx.x & 15;
    const int col = (blk * 256 + threadIdx.x) * 4;
    const int t0  = s * STRIP;
    const int b   = col >> 9;
    const int o   = col & 511;

    const float* xin = X + (size_t)t0 * 16384 + col;
    unsigned short* xout = Xv + (size_t)(t0 * 32 + b) * 512 + o;

    f32x4 v = {0.f, 0.f, 0.f, 0.f};
    if (s > 0) {
        const float* w = xin - (size_t)TAPS * 16384;
        #pragma unroll
        for (int j = 0; j < TAPS; ++j)
            v = PARAM * v + *(const f32x4*)(w + (size_t)j * 16384);
    }

    f32x4 bufA[4], bufB[4];
    #pragma unroll
    for (int j = 0; j < 4; ++j) bufA[j] = *(const f32x4*)(xin + (size_t)j * 16384);

    #pragma unroll
    for (int i = 0; i < STRIP; i += 8) {
        #pragma unroll
        for (int j = 0; j < 4; ++j)
            bufB[j] = *(const f32x4*)(xin + (size_t)(i + 4 + j) * 16384);
        #pragma unroll
        for (int j = 0; j < 4; ++j) {
            v = PARAM * v + bufA[j];
            ushort4 pk; pk.x = f2bf(v[0]); pk.y = f2bf(v[1]); pk.z = f2bf(v[2]); pk.w = f2bf(v[3]);
            *(ushort4*)(xout + (size_t)(i + j) * 16384) = pk;
        }
        if (i + 8 < STRIP) {
            #pragma unroll
            for (int j = 0; j < 4; ++j)
                bufA[j] = *(const f32x4*)(xin + (size_t)(i + 8 + j) * 16384);
        }
        #pragma unroll
        for (int j = 0; j < 4; ++j) {
            v = PARAM * v + bufB[j];
            ushort4 pk; pk.x = f2bf(v[0]); pk.y = f2bf(v[1]); pk.z = f2bf(v[2]); pk.w = f2bf(v[3]);
            *(ushort4*)(xout + (size_t)(i + 4 + j) * 16384) = pk;
        }
    }
}

// --- GEMM: R9 structure (m97 replica: 256 thr / 4 waves, 128x128 tile, BK=64,
// wave-tile 64x64, single-buffer 32KB LDS -> 4 blocks/CU) with SWAPPED-OPERAND
// MFMA: mfma(b,a) yields the Y^T fragment (lane&15 = Y-row, reg j = 4
// consecutive Y-cols) so the epilogue is 16 float4 stores/thread instead of 64
// scalar stores. Pre-swizzled global_load_lds staging; swizzled ds_read. ---
__global__ __launch_bounds__(256, 4) void gemm_kernel(const unsigned short* __restrict__ Xv,
                                                      const unsigned short* __restrict__ Wb,
                                                      const float* __restrict__ bias,
                                                      float* __restrict__ Y) {
    __shared__ __align__(16) short As[BM * BK];   // 16 KB
    __shared__ __align__(16) short Bs[BN * BK];   // 16 KB

    const int tid  = threadIdx.x;
    const int lane = tid & 63;
    const int wave = tid >> 6;        // 0..3
    const int wm   = wave >> 1;       // 0..1
    const int wn   = wave & 1;        // 0..1

    // 4096 blocks: xcd = bid&7; all 4 bn of one mt run temporally close on one
    // XCD -> A panel HBM-fetched once, L2-served 4x; W (512KB) stays L2-hot.
    const int bid = blockIdx.x;
    const int j   = bid >> 3;                     // 0..511
    const int bn  = j & 3;
    const int mt  = (bid & 7) * 128 + (j >> 2);   // 0..1023
    const int row0 = mt * BM;
    const int col0 = bn * BN;

    // Staging: 16B chunks, 8 per 128B row; 4 sets of 32 rows. r&7 = (tid>>3)&7
    // for every set -> swizzled source chunk cs is per-thread constant.
    const int cs = (tid & 7) ^ ((tid >> 3) & 7);
    const unsigned short* aSrc = Xv + (size_t)(row0 + (tid >> 3)) * 512 + cs * 8;
    const unsigned short* bSrc = Wb + (size_t)(col0 + (tid >> 3)) * 512 + cs * 8;

    f32x4 acc[4][4] = {};   // acc[mf][nf]: Y^T frag, reg j = Y-col offset

    for (int ks = 0; ks < NK; ++ks) {
        const int k0 = ks * BK;
        #pragma unroll
        for (int s_ = 0; s_ < 4; ++s_)
            __builtin_amdgcn_global_load_lds(
                (const __attribute__((address_space(1))) unsigned int*)(aSrc + (size_t)s_ * 32 * 512 + k0),
                (__attribute__((address_space(3))) unsigned int*)(As + (s_ * 256 + tid) * 8),
                16, 0, 0);
        #pragma unroll
        for (int s_ = 0; s_ < 4; ++s_)
            __builtin_amdgcn_global_load_lds(
                (const __attribute__((address_space(1))) unsigned int*)(bSrc + (size_t)s_ * 32 * 512 + k0),
                (__attribute__((address_space(3))) unsigned int*)(Bs + (s_ * 256 + tid) * 8),
                16, 0, 0);
        __syncthreads();

        #pragma unroll
        for (int kk = 0; kk < 2; ++kk) {
            const int cc = kk * 4 + (lane >> 4);
            bf16x8 a_[4], b_[4];
            #pragma unroll
            for (int mf = 0; mf < 4; ++mf) {
                const int r = wm * 64 + mf * 16 + (lane & 15);
                a_[mf] = *(const bf16x8*)((const char*)As + r * 128 + ((cc ^ (r & 7)) << 4));
            }
            #pragma unroll
            for (int nf = 0; nf < 4; ++nf) {
                const int r = wn * 64 + nf * 16 + (lane & 15);
                b_[nf] = *(const bf16x8*)((const char*)Bs + r * 128 + ((cc ^ (r & 7)) << 4));
            }
            #pragma unroll
            for (int mf = 0; mf < 4; ++mf)
                #pragma unroll
                for (int nf = 0; nf < 4; ++nf)
                    acc[mf][nf] = __builtin_amdgcn_mfma_f32_16x16x32_bf16(
                        b_[nf], a_[mf], acc[mf][nf], 0, 0, 0);   // SWAPPED -> Y^T frag
        }
        __syncthreads();
    }

    // Epilogue: Y = acc + s[t]*bias, float4 stores (4 consecutive Y-cols/reg).
    // t = grow>>5; grow = row0 + wm*64 + mf*16 + (lane&15) -> t offset = mf>>1.
    float sc4[2];
    #pragma unroll
    for (int tt = 0; tt < 2; ++tt) {
        const int t_ = ((row0 + wm * 64) >> 5) + tt;
        sc4[tt] = (1.0f - __expf(-2.3025851f * (float)(t_ + 1))) * ISCALE;
    }
    f32x4 bvv[4];
    #pragma unroll
    for (int nf = 0; nf < 4; ++nf)
        bvv[nf] = *(const f32x4*)(bias + col0 + wn * 64 + nf * 16 + ((lane >> 4) << 2));

    #pragma unroll
    for (int mf = 0; mf < 4; ++mf) {
        const int grow = row0 + wm * 64 + mf * 16 + (lane & 15);
        const float sc = sc4[mf >> 1];
        #pragma unroll
        for (int nf = 0; nf < 4; ++nf) {
            const int gcol = col0 + wn * 64 + nf * 16 + ((lane >> 4) << 2);
            f32x4 out;
            #pragma unroll
            for (int e = 0; e < 4; ++e) out[e] = acc[mf][nf][e] + sc * bvv[nf][e];
            *(f32x4*)(Y + (size_t)grow * O_DIM + gcol) = out;
        }
    }
}

extern "C" void kernel_launch(void* const* d_in, const int* in_sizes, int n_in,
                              void* d_out, int out_size, void* d_ws, size_t ws_size,
                              hipStream_t stream) {
    const float* X    = (const float*)d_in[0];
    const float* W    = (const float*)d_in[1];
    const float* bias = (const float*)d_in[2];
    float* Y = (float*)d_out;
    unsigned short* Wb = (unsigned short*)d_ws;                       // 512 KB
    unsigned short* Xv = (unsigned short*)((char*)d_ws + (1 << 20));  // 134 MB

    wcvt_kernel<<<dim3(O_DIM * I_DIM / (256 * 4)), dim3(256), 0, stream>>>(W, Wb);
    xema_kernel<<<dim3((T_DIM / STRIP) * 16), dim3(256), 0, stream>>>(X, Xv);
    gemm_kernel<<<dim3((M_DIM / BM) * (O_DIM / BN)), dim3(256), 0, stream>>>(Xv, Wb, bias, Y);
}